// Round 5
// baseline (294.936 us; speedup 1.0000x reference)
//
#include <hip/hip_runtime.h>

typedef __attribute__((ext_vector_type(8))) short bf16x8;
typedef __attribute__((ext_vector_type(4))) float f32x4;
typedef __attribute__((ext_vector_type(8))) unsigned short u16x8;
typedef __attribute__((ext_vector_type(4))) unsigned short u16x4;

#define S_LEN 2048
#define BATCH 2
#define EMB 1024
#define NH 16
#define HDIM 64
#define M_ROWS (S_LEN * BATCH)   // 4096
#define N_QKV (3 * EMB)          // 3072

typedef const __attribute__((address_space(1))) unsigned int* gptr_t;
typedef __attribute__((address_space(3))) unsigned int* lptr_t;

__device__ __forceinline__ unsigned short f2b(float f) {
  union { float f; unsigned u; } v; v.f = f;
  unsigned r = v.u + 0x7fff + ((v.u >> 16) & 1);
  return (unsigned short)(r >> 16);
}
// round-half-up: 1 fewer dependent op chain; P in [0,1], 0.5-ulp class error
__device__ __forceinline__ unsigned short f2b_fast(float f) {
  union { float f; unsigned u; } v; v.f = f;
  return (unsigned short)((v.u + 0x8000u) >> 16);
}
__device__ __forceinline__ float b2f(unsigned short s) {
  union { float f; unsigned u; } v; v.u = ((unsigned)s) << 16;
  return v.f;
}

// ---------------- fp32 -> bf16 conversion (memory-bound) ----------------
__global__ __launch_bounds__(256) void cvt_f32_bf16(const float* __restrict__ in,
                                                    unsigned short* __restrict__ out,
                                                    int n4) {
  int i = blockIdx.x * 256 + threadIdx.x;
  if (i >= n4) return;
  float4 a = reinterpret_cast<const float4*>(in)[i];
  u16x4 o;
  o[0] = f2b(a.x); o[1] = f2b(a.y); o[2] = f2b(a.z); o[3] = f2b(a.w);
  reinterpret_cast<u16x4*>(out)[i] = o;
}

// ---------------- bf16 GEMM, C = A(M,K) * B(N,K)^T ----------------
// 128x128 tile, BK=32, 4 waves (2x2), each wave 64x64 out (4x4 frags of 16x16)
// Staging: global_load_lds width=16, linear LDS (m97 structure)
template <int OUT_BF16>
__global__ __launch_bounds__(256) void gemm_bt(const unsigned short* __restrict__ A,
                                               const unsigned short* __restrict__ Bm,
                                               void* __restrict__ Cv,
                                               int Md, int Nd, int Kd) {
  __shared__ unsigned short As[128][32];  // linear: global_load_lds needs contiguous dest
  __shared__ unsigned short Bs[128][32];
  int t = threadIdx.x;
  int bm = blockIdx.y, bn = blockIdx.x;
  int wid = t >> 6, lane = t & 63;
  int wr = wid >> 1, wc = wid & 1;
  int fr = lane & 15, fq = lane >> 4;
  int lrow = lane >> 2;          // 0..15: row within 16-row chunk
  int lcol = (lane & 3) * 8;     // element col within 32 (16B granules)

  f32x4 acc[4][4];
#pragma unroll
  for (int i = 0; i < 4; ++i)
#pragma unroll
    for (int j = 0; j < 4; ++j) acc[i][j] = (f32x4){0.f, 0.f, 0.f, 0.f};

  int nkt = Kd >> 5;
  for (int kt = 0; kt < nkt; ++kt) {
    // each wave stages 32 rows of A and 32 rows of B (2 chunks of 16 rows each)
    const unsigned short* ga = A + (size_t)(bm * 128 + wid * 32 + lrow) * Kd + kt * 32 + lcol;
    const unsigned short* gb = Bm + (size_t)(bn * 128 + wid * 32 + lrow) * Kd + kt * 32 + lcol;
#pragma unroll
    for (int j = 0; j < 2; ++j) {
      __builtin_amdgcn_global_load_lds((gptr_t)(ga + (size_t)j * 16 * Kd),
                                       (lptr_t)&As[wid * 32 + j * 16][0], 16, 0, 0);
      __builtin_amdgcn_global_load_lds((gptr_t)(gb + (size_t)j * 16 * Kd),
                                       (lptr_t)&Bs[wid * 32 + j * 16][0], 16, 0, 0);
    }
    __syncthreads();   // drains vmcnt -> LDS tiles complete

    bf16x8 af[4], bfv[4];
#pragma unroll
    for (int mt = 0; mt < 4; ++mt)
      af[mt] = *reinterpret_cast<const bf16x8*>(&As[wr * 64 + mt * 16 + fr][fq * 8]);
#pragma unroll
    for (int nt = 0; nt < 4; ++nt)
      bfv[nt] = *reinterpret_cast<const bf16x8*>(&Bs[wc * 64 + nt * 16 + fr][fq * 8]);
#pragma unroll
    for (int mt = 0; mt < 4; ++mt)
#pragma unroll
      for (int nt = 0; nt < 4; ++nt)
        acc[mt][nt] = __builtin_amdgcn_mfma_f32_16x16x32_bf16(af[mt], bfv[nt], acc[mt][nt], 0, 0, 0);
    __syncthreads();
  }

#pragma unroll
  for (int mt = 0; mt < 4; ++mt)
#pragma unroll
    for (int nt = 0; nt < 4; ++nt)
#pragma unroll
      for (int r = 0; r < 4; ++r) {
        int row = bm * 128 + wr * 64 + mt * 16 + fq * 4 + r;
        int col = bn * 128 + wc * 64 + nt * 16 + fr;
        float val = acc[mt][nt][r];
        if (OUT_BF16)
          reinterpret_cast<unsigned short*>(Cv)[(size_t)row * Nd + col] = f2b(val);
        else
          reinterpret_cast<float*>(Cv)[(size_t)row * Nd + col] = val;
      }
}

// ---------------- V transpose: qkv -> Vt[b*16+h][d][s] ----------------
// grid (S/64, B*H). LDS tile [64][72] with chunk-XOR swizzle -> 2-way banks.
__global__ __launch_bounds__(256) void vtrans(const unsigned short* __restrict__ qkv,
                                              unsigned short* __restrict__ vt) {
  __shared__ unsigned short Ts[64][72];
  int t = threadIdx.x;
  int kb = blockIdx.x;
  int bh = blockIdx.y;
  int b = bh >> 4, h = bh & 15;
  int k0 = kb * 64;
#pragma unroll
  for (int i = 0; i < 2; ++i) {
    int c = t + i * 256;
    int r = c >> 3, q = c & 7;                 // V row k0+r, d-chunk q
    int chunk = q ^ ((r >> 3) & 7);            // XOR swizzle (read side matches)
    *reinterpret_cast<u16x8*>(&Ts[r][chunk * 8]) =
        *reinterpret_cast<const u16x8*>(
            qkv + ((size_t)(k0 + r) * BATCH + b) * N_QKV + h * 192 + 128 + q * 8);
  }
  __syncthreads();
#pragma unroll
  for (int i = 0; i < 2; ++i) {
    int c = t + i * 256;
    int d = c >> 3, q = c & 7;                 // output row d, k-chunk q
    u16x8 o;
#pragma unroll
    for (int j = 0; j < 8; ++j) {
      int k = q * 8 + j;
      int chunk = (d >> 3) ^ q;                // (k>>3)&7 == q
      o[j] = Ts[k][chunk * 8 + (d & 7)];
    }
    *reinterpret_cast<u16x8*>(&vt[((size_t)bh * 64 + d) * S_LEN + k0 + q * 8]) = o;
  }
}

// ---------------- flash attention ----------------
// grid: (S/64, B*H); 4 waves, each owns 16 q-rows. KV tiles of 64.
// Double-buffered K/Vt LDS, 1 barrier/tile, T14 early-issue global loads.
__global__ __launch_bounds__(256) void attn_kernel(const unsigned short* __restrict__ qkv,
                                                   const unsigned short* __restrict__ vt,
                                                   unsigned short* __restrict__ att) {
  __shared__ unsigned short Ks[2][64][72];   // [k][d], dbuf
  __shared__ unsigned short VtS[2][64][72];  // [d][k], dbuf
  __shared__ unsigned short Ps[4][16][72];   // per-wave P staging (intra-wave, no barrier)
  int t = threadIdx.x;
  int wid = t >> 6, lane = t & 63;
  int fr = lane & 15, fq = lane >> 4;
  int bh = blockIdx.y;
  int b = bh >> 4;   // H = 16
  int h = bh & 15;
  int q0 = blockIdx.x * 64;

  int srow = t >> 3, sc8 = (t & 7) * 8;      // staging row/col for chunk 0 (chunk1: row+32)

  // Q fragments (A operand): lane holds row fr, k = kc*32 + fq*8 + j
  int qi = q0 + wid * 16 + fr;
  const unsigned short* qrow = qkv + ((size_t)qi * BATCH + b) * N_QKV + h * 192;
  bf16x8 qf[2];
  qf[0] = *reinterpret_cast<const bf16x8*>(qrow + fq * 8);
  qf[1] = *reinterpret_cast<const bf16x8*>(qrow + 32 + fq * 8);
  // pre-scale Q by 1/sqrt(64) = 0.125 (power of 2: exact in bf16)
#pragma unroll
  for (int c = 0; c < 2; ++c)
#pragma unroll
    for (int j = 0; j < 8; ++j)
      qf[c][j] = (short)f2b_fast(0.125f * b2f((unsigned short)qf[c][j]));

  f32x4 o[4];
#pragma unroll
  for (int dt = 0; dt < 4; ++dt) o[dt] = (f32x4){0.f, 0.f, 0.f, 0.f};
  float m_run[4], l_run[4];
#pragma unroll
  for (int r = 0; r < 4; ++r) { m_run[r] = -1e30f; l_run[r] = 0.f; }

  // prologue: stage tile 0 into buf 0
#pragma unroll
  for (int i = 0; i < 2; ++i) {
    int row = srow + i * 32;
    *reinterpret_cast<u16x8*>(&Ks[0][row][sc8]) = *reinterpret_cast<const u16x8*>(
        qkv + ((size_t)row * BATCH + b) * N_QKV + h * 192 + 64 + sc8);
    *reinterpret_cast<u16x8*>(&VtS[0][row][sc8]) = *reinterpret_cast<const u16x8*>(
        vt + ((size_t)bh * 64 + row) * S_LEN + sc8);
  }
  __syncthreads();

  for (int kt = 0; kt < S_LEN / 64; ++kt) {
    int cur = kt & 1, nxt = cur ^ 1;

    // T14: issue next tile's global loads first; they complete under compute
    u16x8 kreg[2], vreg[2];
    if (kt + 1 < S_LEN / 64) {
#pragma unroll
      for (int i = 0; i < 2; ++i) {
        int row = srow + i * 32;
        kreg[i] = *reinterpret_cast<const u16x8*>(
            qkv + ((size_t)((kt + 1) * 64 + row) * BATCH + b) * N_QKV + h * 192 + 64 + sc8);
        vreg[i] = *reinterpret_cast<const u16x8*>(
            vt + ((size_t)bh * 64 + row) * S_LEN + (kt + 1) * 64 + sc8);
      }
    }

    // S = Q * K^T  (each wave: 16 x 64); Q pre-scaled
    f32x4 sf[4];
#pragma unroll
    for (int nt = 0; nt < 4; ++nt) {
      bf16x8 bk0 = *reinterpret_cast<const bf16x8*>(&Ks[cur][nt * 16 + fr][fq * 8]);
      bf16x8 bk1 = *reinterpret_cast<const bf16x8*>(&Ks[cur][nt * 16 + fr][32 + fq * 8]);
      f32x4 s = (f32x4){0.f, 0.f, 0.f, 0.f};
      s = __builtin_amdgcn_mfma_f32_16x16x32_bf16(qf[0], bk0, s, 0, 0, 0);
      s = __builtin_amdgcn_mfma_f32_16x16x32_bf16(qf[1], bk1, s, 0, 0, 0);
      sf[nt] = s;
    }

    // online softmax; lane holds rows fq*4+r, col fr + nt*16
    float p[4][4];
#pragma unroll
    for (int r = 0; r < 4; ++r) {
      float mx = fmaxf(fmaxf(sf[0][r], sf[1][r]), fmaxf(sf[2][r], sf[3][r]));
#pragma unroll
      for (int m = 1; m < 16; m <<= 1) mx = fmaxf(mx, __shfl_xor(mx, m));
      float mnew = fmaxf(m_run[r], mx);
      float alpha = __expf(m_run[r] - mnew);
      m_run[r] = mnew;
      float rs = 0.f;
#pragma unroll
      for (int nt = 0; nt < 4; ++nt) {
        float pv = __expf(sf[nt][r] - mnew);
        p[nt][r] = pv;
        rs += pv;
      }
#pragma unroll
      for (int m = 1; m < 16; m <<= 1) rs += __shfl_xor(rs, m);
      l_run[r] = l_run[r] * alpha + rs;
#pragma unroll
      for (int dt = 0; dt < 4; ++dt) o[dt][r] *= alpha;
    }

    // P -> LDS (bf16), reshape C-layout -> A-layout (same wave: no barrier needed)
#pragma unroll
    for (int nt = 0; nt < 4; ++nt)
#pragma unroll
      for (int r = 0; r < 4; ++r)
        Ps[wid][fq * 4 + r][nt * 16 + fr] = f2b_fast(p[nt][r]);

    // O += P * V : B-fragment = VtS[d][k] row-major -> vectorized b128
#pragma unroll
    for (int kc = 0; kc < 2; ++kc) {
      bf16x8 pa = *reinterpret_cast<const bf16x8*>(&Ps[wid][fr][kc * 32 + fq * 8]);
#pragma unroll
      for (int dt = 0; dt < 4; ++dt) {
        bf16x8 vb = *reinterpret_cast<const bf16x8*>(&VtS[cur][dt * 16 + fr][kc * 32 + fq * 8]);
        o[dt] = __builtin_amdgcn_mfma_f32_16x16x32_bf16(pa, vb, o[dt], 0, 0, 0);
      }
    }

    // write next tile to the other buffer (readers of it finished before last barrier)
    if (kt + 1 < S_LEN / 64) {
#pragma unroll
      for (int i = 0; i < 2; ++i) {
        int row = srow + i * 32;
        *reinterpret_cast<u16x8*>(&Ks[nxt][row][sc8]) = kreg[i];
        *reinterpret_cast<u16x8*>(&VtS[nxt][row][sc8]) = vreg[i];
      }
    }
    __syncthreads();   // single barrier per tile
  }

  // epilogue: O /= l, write bf16 to att[(q*B+b)*E + h*64 + d]
#pragma unroll
  for (int dt = 0; dt < 4; ++dt)
#pragma unroll
    for (int r = 0; r < 4; ++r) {
      int q = q0 + wid * 16 + fq * 4 + r;
      int d = dt * 16 + fr;
      float val = o[dt][r] / l_run[r];
      att[((size_t)q * BATCH + b) * EMB + h * 64 + d] = f2b(val);
    }
}

extern "C" void kernel_launch(void* const* d_in, const int* in_sizes, int n_in,
                              void* d_out, int out_size, void* d_ws, size_t ws_size,
                              hipStream_t stream) {
  const float* q_in  = (const float*)d_in[0];
  const float* w_in  = (const float*)d_in[3];
  const float* w_out = (const float*)d_in[4];
  float* out = (float*)d_out;

  unsigned short* ws  = (unsigned short*)d_ws;
  unsigned short* Xb  = ws;                                  // 4096x1024 (dead after gemm1)
  unsigned short* Wb  = Xb + (size_t)M_ROWS * EMB;           // 3072x1024
  unsigned short* Ob  = Wb + (size_t)N_QKV * EMB;            // 1024x1024
  unsigned short* QKV = Ob + (size_t)EMB * EMB;              // 4096x3072
  unsigned short* ATT = QKV + (size_t)M_ROWS * N_QKV;        // 4096x1024
  unsigned short* Vt  = Xb;                                  // alias: 32*64*2048 == 4096*1024

  cvt_f32_bf16<<<(M_ROWS * EMB / 4 + 255) / 256, 256, 0, stream>>>(q_in, Xb, M_ROWS * EMB / 4);
  cvt_f32_bf16<<<(N_QKV * EMB / 4 + 255) / 256, 256, 0, stream>>>(w_in, Wb, N_QKV * EMB / 4);
  cvt_f32_bf16<<<(EMB * EMB / 4 + 255) / 256, 256, 0, stream>>>(w_out, Ob, EMB * EMB / 4);

  gemm_bt<1><<<dim3(N_QKV / 128, M_ROWS / 128), 256, 0, stream>>>(Xb, Wb, QKV, M_ROWS, N_QKV, EMB);
  vtrans<<<dim3(S_LEN / 64, BATCH * NH), 256, 0, stream>>>(QKV, Vt);
  attn_kernel<<<dim3(S_LEN / 64, BATCH * NH), 256, 0, stream>>>(QKV, Vt, ATT);
  gemm_bt<0><<<dim3(EMB / 128, M_ROWS / 128), 256, 0, stream>>>(ATT, Ob, out, M_ROWS, EMB, EMB);
}

// Round 8
// 253.737 us; speedup vs baseline: 1.1624x; 1.1624x over previous
//
#include <hip/hip_runtime.h>

typedef __attribute__((ext_vector_type(8))) short bf16x8;
typedef __attribute__((ext_vector_type(4))) float f32x4;
typedef __attribute__((ext_vector_type(8))) unsigned short u16x8;
typedef __attribute__((ext_vector_type(4))) unsigned short u16x4;

#define S_LEN 2048
#define BATCH 2
#define EMB 1024
#define NH 16
#define HDIM 64
#define M_ROWS (S_LEN * BATCH)   // 4096
#define N_QKV (3 * EMB)          // 3072

typedef const __attribute__((address_space(1))) unsigned int* gptr_t;
typedef __attribute__((address_space(3))) unsigned int* lptr_t;

__device__ __forceinline__ unsigned short f2b(float f) {
  union { float f; unsigned u; } v; v.f = f;
  unsigned r = v.u + 0x7fff + ((v.u >> 16) & 1);
  return (unsigned short)(r >> 16);
}
// round-half-up: shorter dep chain; fine for P in [0,1]
__device__ __forceinline__ unsigned short f2b_fast(float f) {
  union { float f; unsigned u; } v; v.f = f;
  return (unsigned short)((v.u + 0x8000u) >> 16);
}
__device__ __forceinline__ float b2f(unsigned short s) {
  union { float f; unsigned u; } v; v.u = ((unsigned)s) << 16;
  return v.f;
}

// ---------------- fp32 -> bf16 conversion (memory-bound) ----------------
__global__ __launch_bounds__(256) void cvt_f32_bf16(const float* __restrict__ in,
                                                    unsigned short* __restrict__ out,
                                                    int n4) {
  int i = blockIdx.x * 256 + threadIdx.x;
  if (i >= n4) return;
  float4 a = reinterpret_cast<const float4*>(in)[i];
  u16x4 o;
  o[0] = f2b(a.x); o[1] = f2b(a.y); o[2] = f2b(a.z); o[3] = f2b(a.w);
  reinterpret_cast<u16x4*>(out)[i] = o;
}

// ---------------- bf16 GEMM, C = A(M,K) * B(N,K)^T ----------------
// 128x128 tile, BK=32, 4 waves (2x2), each wave 64x64 out (4x4 frags of 16x16)
// Staging: global_load_lds width=16, linear LDS (m97 structure)
template <int OUT_BF16>
__global__ __launch_bounds__(256) void gemm_bt(const unsigned short* __restrict__ A,
                                               const unsigned short* __restrict__ Bm,
                                               void* __restrict__ Cv,
                                               int Md, int Nd, int Kd) {
  __shared__ unsigned short As[128][32];  // linear: global_load_lds needs contiguous dest
  __shared__ unsigned short Bs[128][32];
  int t = threadIdx.x;
  int bm = blockIdx.y, bn = blockIdx.x;
  int wid = t >> 6, lane = t & 63;
  int wr = wid >> 1, wc = wid & 1;
  int fr = lane & 15, fq = lane >> 4;
  int lrow = lane >> 2;          // 0..15: row within 16-row chunk
  int lcol = (lane & 3) * 8;     // element col within 32 (16B granules)

  f32x4 acc[4][4];
#pragma unroll
  for (int i = 0; i < 4; ++i)
#pragma unroll
    for (int j = 0; j < 4; ++j) acc[i][j] = (f32x4){0.f, 0.f, 0.f, 0.f};

  int nkt = Kd >> 5;
  for (int kt = 0; kt < nkt; ++kt) {
    // each wave stages 32 rows of A and 32 rows of B (2 chunks of 16 rows each)
    const unsigned short* ga = A + (size_t)(bm * 128 + wid * 32 + lrow) * Kd + kt * 32 + lcol;
    const unsigned short* gb = Bm + (size_t)(bn * 128 + wid * 32 + lrow) * Kd + kt * 32 + lcol;
#pragma unroll
    for (int j = 0; j < 2; ++j) {
      __builtin_amdgcn_global_load_lds((gptr_t)(ga + (size_t)j * 16 * Kd),
                                       (lptr_t)&As[wid * 32 + j * 16][0], 16, 0, 0);
      __builtin_amdgcn_global_load_lds((gptr_t)(gb + (size_t)j * 16 * Kd),
                                       (lptr_t)&Bs[wid * 32 + j * 16][0], 16, 0, 0);
    }
    __syncthreads();   // drains vmcnt -> LDS tiles complete

    bf16x8 af[4], bfv[4];
#pragma unroll
    for (int mt = 0; mt < 4; ++mt)
      af[mt] = *reinterpret_cast<const bf16x8*>(&As[wr * 64 + mt * 16 + fr][fq * 8]);
#pragma unroll
    for (int nt = 0; nt < 4; ++nt)
      bfv[nt] = *reinterpret_cast<const bf16x8*>(&Bs[wc * 64 + nt * 16 + fr][fq * 8]);
#pragma unroll
    for (int mt = 0; mt < 4; ++mt)
#pragma unroll
      for (int nt = 0; nt < 4; ++nt)
        acc[mt][nt] = __builtin_amdgcn_mfma_f32_16x16x32_bf16(af[mt], bfv[nt], acc[mt][nt], 0, 0, 0);
    __syncthreads();
  }

#pragma unroll
  for (int mt = 0; mt < 4; ++mt)
#pragma unroll
    for (int nt = 0; nt < 4; ++nt)
#pragma unroll
      for (int r = 0; r < 4; ++r) {
        int row = bm * 128 + wr * 64 + mt * 16 + fq * 4 + r;
        int col = bn * 128 + wc * 64 + nt * 16 + fr;
        float val = acc[mt][nt][r];
        if (OUT_BF16)
          reinterpret_cast<unsigned short*>(Cv)[(size_t)row * Nd + col] = f2b(val);
        else
          reinterpret_cast<float*>(Cv)[(size_t)row * Nd + col] = val;
      }
}

// ---------------- V transpose: qkv -> Vt[b*16+h][d][s] ----------------
// grid (S/64, B*H). LDS tile [64][72] with chunk-XOR swizzle -> 2-way banks.
__global__ __launch_bounds__(256) void vtrans(const unsigned short* __restrict__ qkv,
                                              unsigned short* __restrict__ vt) {
  __shared__ unsigned short Ts[64][72];
  int t = threadIdx.x;
  int kb = blockIdx.x;
  int bh = blockIdx.y;
  int b = bh >> 4, h = bh & 15;
  int k0 = kb * 64;
#pragma unroll
  for (int i = 0; i < 2; ++i) {
    int c = t + i * 256;
    int r = c >> 3, q = c & 7;                 // V row k0+r, d-chunk q
    int chunk = q ^ ((r >> 3) & 7);            // XOR swizzle (read side matches)
    *reinterpret_cast<u16x8*>(&Ts[r][chunk * 8]) =
        *reinterpret_cast<const u16x8*>(
            qkv + ((size_t)(k0 + r) * BATCH + b) * N_QKV + h * 192 + 128 + q * 8);
  }
  __syncthreads();
#pragma unroll
  for (int i = 0; i < 2; ++i) {
    int c = t + i * 256;
    int d = c >> 3, q = c & 7;                 // output row d, k-chunk q
    u16x8 o;
#pragma unroll
    for (int j = 0; j < 8; ++j) {
      int k = q * 8 + j;
      int chunk = (d >> 3) ^ q;                // (k>>3)&7 == q
      o[j] = Ts[k][chunk * 8 + (d & 7)];
    }
    *reinterpret_cast<u16x8*>(&vt[((size_t)bh * 64 + d) * S_LEN + k0 + q * 8]) = o;
  }
}

// ---------------- flash attention (swapped-operand, in-register softmax) ----
// grid: (S/64, B*H); 4 waves x 16 q-rows. KV tiles of 64. dbuf K/Vt LDS.
// QK^T computed as mfma(K, Q) -> lane holds S[q=fr][k=nt*16+fq*4+r]:
// softmax is lane-local + 2 shfl_xor; P redistributed to B-operand layout
// via shuffles (no Ps LDS, no bank conflicts).
__global__ __launch_bounds__(256) void attn_kernel(const unsigned short* __restrict__ qkv,
                                                   const unsigned short* __restrict__ vt,
                                                   unsigned short* __restrict__ att) {
  __shared__ unsigned short Ks[2][64][72];   // [k][d], dbuf
  __shared__ unsigned short VtS[2][64][72];  // [d][k], dbuf
  int t = threadIdx.x;
  int wid = t >> 6, lane = t & 63;
  int fr = lane & 15, fq = lane >> 4;
  int bh = blockIdx.y;
  int b = bh >> 4;   // H = 16
  int h = bh & 15;
  int q0 = blockIdx.x * 64;

  int srow = t >> 3, sc8 = (t & 7) * 8;      // staging row/col (chunk1: row+32)

  // Q fragments (B operand now): lane holds q-row fr, d = c*32 + fq*8 + j
  int qi = q0 + wid * 16 + fr;
  const unsigned short* qrow = qkv + ((size_t)qi * BATCH + b) * N_QKV + h * 192;
  bf16x8 qf[2];
  qf[0] = *reinterpret_cast<const bf16x8*>(qrow + fq * 8);
  qf[1] = *reinterpret_cast<const bf16x8*>(qrow + 32 + fq * 8);
  // pre-scale Q by 1/sqrt(64) = 0.125 (power of 2: exact in bf16)
#pragma unroll
  for (int c = 0; c < 2; ++c)
#pragma unroll
    for (int j = 0; j < 8; ++j)
      qf[c][j] = (short)f2b_fast(0.125f * b2f((unsigned short)qf[c][j]));

  // O^T accumulator: lane holds q=fr, d = dt*16 + fq*4 + r
  f32x4 o[4];
#pragma unroll
  for (int dt = 0; dt < 4; ++dt) o[dt] = (f32x4){0.f, 0.f, 0.f, 0.f};
  float m_run = -1e30f, l_run = 0.f;

  // redistribution constants
  int srcA = fr + ((fq & 1) << 5);   // fr + 32*(fq&1)
  int srcB = srcA + 16;
  int hi = (fq >> 1) & 1;

  // prologue: stage tile 0 into buf 0
#pragma unroll
  for (int i = 0; i < 2; ++i) {
    int row = srow + i * 32;
    *reinterpret_cast<u16x8*>(&Ks[0][row][sc8]) = *reinterpret_cast<const u16x8*>(
        qkv + ((size_t)row * BATCH + b) * N_QKV + h * 192 + 64 + sc8);
    *reinterpret_cast<u16x8*>(&VtS[0][row][sc8]) = *reinterpret_cast<const u16x8*>(
        vt + ((size_t)bh * 64 + row) * S_LEN + sc8);
  }
  __syncthreads();

  for (int kt = 0; kt < S_LEN / 64; ++kt) {
    int cur = kt & 1, nxt = cur ^ 1;

    // T14: issue next tile's global loads first; complete under compute
    u16x8 kreg[2], vreg[2];
    if (kt + 1 < S_LEN / 64) {
#pragma unroll
      for (int i = 0; i < 2; ++i) {
        int row = srow + i * 32;
        kreg[i] = *reinterpret_cast<const u16x8*>(
            qkv + ((size_t)((kt + 1) * 64 + row) * BATCH + b) * N_QKV + h * 192 + 64 + sc8);
        vreg[i] = *reinterpret_cast<const u16x8*>(
            vt + ((size_t)bh * 64 + row) * S_LEN + (kt + 1) * 64 + sc8);
      }
    }

    // S^T = K * Q^T : mfma(A=K rows, B=Q rows). Lane: q=fr, k=nt*16+fq*4+r
    f32x4 snt[4];
#pragma unroll
    for (int nt = 0; nt < 4; ++nt) {
      bf16x8 bk0 = *reinterpret_cast<const bf16x8*>(&Ks[cur][nt * 16 + fr][fq * 8]);
      bf16x8 bk1 = *reinterpret_cast<const bf16x8*>(&Ks[cur][nt * 16 + fr][32 + fq * 8]);
      f32x4 s = (f32x4){0.f, 0.f, 0.f, 0.f};
      s = __builtin_amdgcn_mfma_f32_16x16x32_bf16(bk0, qf[0], s, 0, 0, 0);
      s = __builtin_amdgcn_mfma_f32_16x16x32_bf16(bk1, qf[1], s, 0, 0, 0);
      snt[nt] = s;
    }

    // online softmax: lane-local over 16 values + 2 shfl_xor (4-lane group)
    float mx = fmaxf(fmaxf(fmaxf(snt[0][0], snt[0][1]), fmaxf(snt[0][2], snt[0][3])),
                     fmaxf(fmaxf(snt[1][0], snt[1][1]), fmaxf(snt[1][2], snt[1][3])));
    mx = fmaxf(mx, fmaxf(fmaxf(fmaxf(snt[2][0], snt[2][1]), fmaxf(snt[2][2], snt[2][3])),
                         fmaxf(fmaxf(snt[3][0], snt[3][1]), fmaxf(snt[3][2], snt[3][3]))));
    mx = fmaxf(mx, __shfl_xor(mx, 16));
    mx = fmaxf(mx, __shfl_xor(mx, 32));
    float mnew = fmaxf(m_run, mx);
    float alpha = __expf(m_run - mnew);
    m_run = mnew;
    float rs = 0.f;
#pragma unroll
    for (int nt = 0; nt < 4; ++nt)
#pragma unroll
      for (int r = 0; r < 4; ++r) {
        float pv = __expf(snt[nt][r] - mnew);
        snt[nt][r] = pv;
        rs += pv;
      }
    rs += __shfl_xor(rs, 16);
    rs += __shfl_xor(rs, 32);
    l_run = l_run * alpha + rs;
#pragma unroll
    for (int dt = 0; dt < 4; ++dt) o[dt] *= alpha;

    // pack P to bf16 dwords: pd[nt*2+h] = (p[nt][2h], p[nt][2h+1])
    unsigned pd[8];
#pragma unroll
    for (int nt = 0; nt < 4; ++nt)
#pragma unroll
      for (int hh = 0; hh < 2; ++hh)
        pd[nt * 2 + hh] = (unsigned)f2b_fast(snt[nt][2 * hh]) |
                          ((unsigned)f2b_fast(snt[nt][2 * hh + 1]) << 16);

    // redistribute to B-operand layout and do PV:
    // dest dword dwi of kc needs src lane (fr+32*(fq&1)+16*(dwi>>1)),
    // src dword 4kc + 2*(fq>>1) + (dwi&1)   [hand-verified mapping]
#pragma unroll
    for (int kc = 0; kc < 2; ++kc) {
      int base = kc * 4;
      unsigned a0 = (unsigned)__shfl((int)pd[base + 0], srcA);
      unsigned a1 = (unsigned)__shfl((int)pd[base + 1], srcA);
      unsigned a2 = (unsigned)__shfl((int)pd[base + 2], srcA);
      unsigned a3 = (unsigned)__shfl((int)pd[base + 3], srcA);
      unsigned c0 = (unsigned)__shfl((int)pd[base + 0], srcB);
      unsigned c1 = (unsigned)__shfl((int)pd[base + 1], srcB);
      unsigned c2 = (unsigned)__shfl((int)pd[base + 2], srcB);
      unsigned c3 = (unsigned)__shfl((int)pd[base + 3], srcB);
      union { unsigned u[4]; bf16x8 v; } pb;
      pb.u[0] = hi ? a2 : a0;
      pb.u[1] = hi ? a3 : a1;
      pb.u[2] = hi ? c2 : c0;
      pb.u[3] = hi ? c3 : c1;
#pragma unroll
      for (int dt = 0; dt < 4; ++dt) {
        bf16x8 vb = *reinterpret_cast<const bf16x8*>(&VtS[cur][dt * 16 + fr][kc * 32 + fq * 8]);
        o[dt] = __builtin_amdgcn_mfma_f32_16x16x32_bf16(vb, pb.v, o[dt], 0, 0, 0);
      }
    }

    // write next tile to the other buffer
    if (kt + 1 < S_LEN / 64) {
#pragma unroll
      for (int i = 0; i < 2; ++i) {
        int row = srow + i * 32;
        *reinterpret_cast<u16x8*>(&Ks[nxt][row][sc8]) = kreg[i];
        *reinterpret_cast<u16x8*>(&VtS[nxt][row][sc8]) = vreg[i];
      }
    }
    __syncthreads();   // single barrier per tile
  }

  // epilogue: O^T lane layout q=fr, d = dt*16+fq*4+r (r contiguous -> u16x4)
  float invl = 1.0f / l_run;
  int q = q0 + wid * 16 + fr;
#pragma unroll
  for (int dt = 0; dt < 4; ++dt) {
    u16x4 ov;
#pragma unroll
    for (int r = 0; r < 4; ++r) ov[r] = f2b(o[dt][r] * invl);
    int d = dt * 16 + fq * 4;
    *reinterpret_cast<u16x4*>(&att[((size_t)q * BATCH + b) * EMB + h * 64 + d]) = ov;
  }
}

extern "C" void kernel_launch(void* const* d_in, const int* in_sizes, int n_in,
                              void* d_out, int out_size, void* d_ws, size_t ws_size,
                              hipStream_t stream) {
  const float* q_in  = (const float*)d_in[0];
  const float* w_in  = (const float*)d_in[3];
  const float* w_out = (const float*)d_in[4];
  float* out = (float*)d_out;

  unsigned short* ws  = (unsigned short*)d_ws;
  unsigned short* Xb  = ws;                                  // 4096x1024 (dead after gemm1)
  unsigned short* Wb  = Xb + (size_t)M_ROWS * EMB;           // 3072x1024
  unsigned short* Ob  = Wb + (size_t)N_QKV * EMB;            // 1024x1024
  unsigned short* QKV = Ob + (size_t)EMB * EMB;              // 4096x3072
  unsigned short* ATT = QKV + (size_t)M_ROWS * N_QKV;        // 4096x1024
  unsigned short* Vt  = Xb;                                  // alias: 32*64*2048 == 4096*1024

  cvt_f32_bf16<<<(M_ROWS * EMB / 4 + 255) / 256, 256, 0, stream>>>(q_in, Xb, M_ROWS * EMB / 4);
  cvt_f32_bf16<<<(N_QKV * EMB / 4 + 255) / 256, 256, 0, stream>>>(w_in, Wb, N_QKV * EMB / 4);
  cvt_f32_bf16<<<(EMB * EMB / 4 + 255) / 256, 256, 0, stream>>>(w_out, Ob, EMB * EMB / 4);

  gemm_bt<1><<<dim3(N_QKV / 128, M_ROWS / 128), 256, 0, stream>>>(Xb, Wb, QKV, M_ROWS, N_QKV, EMB);
  vtrans<<<dim3(S_LEN / 64, BATCH * NH), 256, 0, stream>>>(QKV, Vt);
  attn_kernel<<<dim3(S_LEN / 64, BATCH * NH), 256, 0, stream>>>(QKV, Vt, ATT);
  gemm_bt<0><<<dim3(EMB / 128, M_ROWS / 128), 256, 0, stream>>>(ATT, Ob, out, M_ROWS, EMB, EMB);
}